// Round 2
// baseline (177.131 us; speedup 1.0000x reference)
//
#include <hip/hip_runtime.h>
#include <hip/hip_bf16.h>
#include <string.h>

typedef __hip_bfloat16 bf16;
typedef __attribute__((ext_vector_type(8))) short short8;
typedef __attribute__((ext_vector_type(4))) short short4v;
typedef __attribute__((ext_vector_type(4))) float f32x4;

__device__ __forceinline__ float b2f(bf16 v) { return __bfloat162float(v); }
__device__ __forceinline__ bf16  f2b(float v) { return __float2bfloat16(v); }
__device__ __forceinline__ float s2f(short s) {
    return __uint_as_float(((unsigned)(unsigned short)s) << 16);
}
__device__ __forceinline__ short f2s(float v) {
    bf16 t = f2b(v); short s; __builtin_memcpy(&s, &t, 2); return s;
}

#define HWD 16384    // 128*128

// ---------------------------------------------------------------------------
// K01: transpose x (b,256,4096) fp32 -> xpm (b,4096,256) bf16 via swizzled
// LDS tile, then MFMA the off/ast GEMM straight from LDS.
// grid 256 = 4 b * 64 tiles(64 px); 512 threads (8 waves: 2 m-halves x 4 N).
// ---------------------------------------------------------------------------
__global__ __launch_bounds__(512) void k01_xpose_off(const float* __restrict__ x,
        const float* __restrict__ w_off, const float* __restrict__ b_off,
        const float* __restrict__ w_ast, const float* __restrict__ b_ast,
        bf16* __restrict__ xpm, float* __restrict__ offpm)
{
    __shared__ __align__(16) short tileS[64 * 256];   // 32 KB, swizzled
    const int b = blockIdx.x >> 6;
    const int p0 = (blockIdx.x & 63) << 6;
    const int lane = threadIdx.x & 63;
    const int wave = threadIdx.x >> 6;      // 0..7
    const int n = lane & 15, quad = lane >> 4;
    const int wq = wave & 3;                // N-group
    const int mh = wave >> 2;               // m-half (rows mh*32..mh*32+31)

    // --- B fragments (dup across mh) ---
    const int j = (wq << 4) + n, oc = j >> 1, kind = j & 1;
    short8 bfrag[8];
    const float* wrow = (kind ? w_ast : w_off) + oc * 256 + quad * 8;
#pragma unroll
    for (int kc = 0; kc < 8; ++kc) {
        float4 lo = *(const float4*)(wrow + kc * 32);
        float4 hi = *(const float4*)(wrow + kc * 32 + 4);
        short8 f;
        f[0] = f2s(lo.x); f[1] = f2s(lo.y); f[2] = f2s(lo.z); f[3] = f2s(lo.w);
        f[4] = f2s(hi.x); f[5] = f2s(hi.y); f[6] = f2s(hi.z); f[7] = f2s(hi.w);
        bfrag[kc] = f;
    }
    float bias = kind ? b_ast[oc] : b_off[oc];

    // --- phase 1: fill swizzled LDS tile (each wave: 32 channels x 64 px) ---
    {
        const float* xb = x + ((size_t)b << 20);
        const int lp = lane;
#pragma unroll
        for (int gg = 0; gg < 4; ++gg) {
            int cbase = (wave << 5) + (gg << 3);
            short8 pk;
#pragma unroll
            for (int jj = 0; jj < 8; ++jj)
                pk[jj] = f2s(xb[((size_t)(cbase + jj) << 12) + p0 + lp]);
            int slot = (cbase >> 3) ^ (lp & 7);
            *(short8*)&tileS[(lp << 8) + (slot << 3)] = pk;
        }
    }
    __syncthreads();

    // --- phase 2: coalesced xpm store from LDS (8 rows per wave) ---
    {
        short* ob = (short*)xpm + ((size_t)((b << 12) + p0) << 8);
#pragma unroll
        for (int rr = 0; rr < 8; ++rr) {
            int r = (wave << 3) + rr;
            short4v v = *(const short4v*)&tileS[(r << 8)
                        + ((((lane >> 1) ^ (r & 7)) << 3) | ((lane & 1) << 2))];
            *(short4v*)(ob + ((size_t)r << 8) + (lane << 2)) = v;
        }
    }

    // --- phase 3: MFMA GEMM from LDS, gated epilogue -> offpm ---
    float* obase = offpm + ((size_t)(b << 12) << 5);
    f32x4 acc0 = {0.f, 0.f, 0.f, 0.f};
    f32x4 acc1 = {0.f, 0.f, 0.f, 0.f};
#pragma unroll
    for (int kc = 0; kc < 8; ++kc) {
        int slot = (((kc << 2) + quad) ^ (n & 7)) << 3;
        short8 a0 = *(const short8*)&tileS[((mh * 32 + n) << 8) + slot];
        short8 a1 = *(const short8*)&tileS[((mh * 32 + 16 + n) << 8) + slot];
        acc0 = __builtin_amdgcn_mfma_f32_16x16x32_bf16(a0, bfrag[kc], acc0, 0, 0, 0);
        acc1 = __builtin_amdgcn_mfma_f32_16x16x32_bf16(a1, bfrag[kc], acc1, 0, 0, 0);
    }
#pragma unroll
    for (int r = 0; r < 4; ++r) {
        float v0 = acc0[r] + bias;
        float v1 = acc1[r] + bias;
        float p0v = __shfl_xor(v0, 1, 64);
        float p1v = __shfl_xor(v1, 1, 64);
        if (!(n & 1)) {
            int px = p0 + mh * 32 + quad * 4 + r;
            obase[((size_t)px << 5) + oc] = v0 * (1.f / (1.f + expf(-p0v)));
            obase[((size_t)(px + 16) << 5) + oc] = v1 * (1.f / (1.f + expf(-p1v)));
        }
    }
}

// ---------------------------------------------------------------------------
// K234 (fused def_sample + comp MFMA + kern/toff epilogue + 3x3 dyn filter):
// grid 1024 = 4 b * 256 tiles(8x8 px + 1-px halo = 10x10 gathered).
// xup never touches global; kern stays in LDS; writes xfilt + toff only.
// LDS: xupS 50K + smc 16.6K + fwS 3K + swS 4K + kernS 2.25K ~= 75.5 KB.
// ---------------------------------------------------------------------------
__global__ __launch_bounds__(256, 2) void k234_defsample_comp_filter(
        const bf16* __restrict__ xpm, const float* __restrict__ offpm,
        const float* __restrict__ cw, const float* __restrict__ cb,
        const float* __restrict__ fw_g, const float* __restrict__ fb,
        const float* __restrict__ tw, const float* __restrict__ tb,
        const float* __restrict__ taw, const float* __restrict__ tab,
        bf16* __restrict__ xfilt, float* __restrict__ toff)
{
    __shared__ __align__(16) short xupS[100 * 256];   // 50 KB, swizzled rows
    __shared__ __align__(16) float smc[64][65];       // comp redistribution
    __shared__ __align__(16) float fwS[64 * 12];
    __shared__ __align__(16) float swS[64 * 16];
    __shared__ __align__(16) short kernS[64][18];

    for (int i = threadIdx.x; i < 64 * 12; i += 256) {
        int c = i / 12, k = i % 12;
        fwS[i] = (k < 9) ? fw_g[k * 64 + c] : 0.f;
    }
    for (int i = threadIdx.x; i < 64 * 16; i += 256) {
        int c = i >> 4, jj = i & 15;
        int oc = jj >> 1, kind = jj & 1;
        swS[i] = kind ? taw[oc * 64 + c] : tw[oc * 64 + c];
    }

    const int b = blockIdx.x >> 8;
    const int tile = blockIdx.x & 255;
    const int ty = tile >> 4, tx = tile & 15;     // 8x8-px tile origin /8
    const int lane = threadIdx.x & 63;
    const int wave = threadIdx.x >> 6;
    const int n = lane & 15, quad = lane >> 4;
    const int ocb = wave << 4;

    // --- B fragments for comp GEMM ---
    short8 bfrag[8];
    const float* wrow = cw + (ocb + n) * 256 + quad * 8;
#pragma unroll
    for (int kc = 0; kc < 8; ++kc) {
        float4 lo = *(const float4*)(wrow + kc * 32);
        float4 hi = *(const float4*)(wrow + kc * 32 + 4);
        short8 f;
        f[0] = f2s(lo.x); f[1] = f2s(lo.y); f[2] = f2s(lo.z); f[3] = f2s(lo.w);
        f[4] = f2s(hi.x); f[5] = f2s(hi.y); f[6] = f2s(hi.z); f[7] = f2s(hi.w);
        bfrag[kc] = f;
    }
    float bias = cb[ocb + n];

    // --- phase 1: gather 25 halo pixels per wave into swizzled LDS ---
    {
        const short* xsrc = (const short*)xpm + ((size_t)b << 20);
        const int e = lane << 2;              // 4-channel chunk (shorts)
        const int g = lane >> 4;
#pragma unroll 5
        for (int i = 0; i < 25; ++i) {
            int l = wave * 25 + i;            // local halo px 0..99
            int lhy = (l * 205) >> 11;        // l / 10
            int lwx = l - lhy * 10;
            int hy = ty * 8 - 1 + lhy;  hy = min(max(hy, 0), 127);
            int wx = tx * 8 - 1 + lwx;  wx = min(max(wx, 0), 127);
            int h = hy >> 1, w = wx >> 1;
            int och = (g << 3) + ((hy & 1) << 2) + ((wx & 1) << 1);
            const float* orow = offpm + ((size_t)((b << 12) + (h << 6) + w) << 5);
            float ox = orow[och], oy = orow[och + 1];
            float ix = (wx + 0.5f + ox) * 0.5f - 0.5f;
            float iy = (hy + 0.5f + oy) * 0.5f - 0.5f;
            ix = fminf(fmaxf(ix, 0.f), 63.f);
            iy = fminf(fmaxf(iy, 0.f), 63.f);
            float x0f = floorf(ix), y0f = floorf(iy);
            float fx = ix - x0f, fy = iy - y0f;
            int x0 = (int)x0f, y0 = (int)y0f;
            int x1 = min(x0 + 1, 63), y1 = min(y0 + 1, 63);
            float w00 = (1.f - fx) * (1.f - fy), w01 = fx * (1.f - fy);
            float w10 = (1.f - fx) * fy,        w11 = fx * fy;
            short4v v00 = *(const short4v*)(xsrc + (((size_t)(y0 << 6) + x0) << 8) + e);
            short4v v01 = *(const short4v*)(xsrc + (((size_t)(y0 << 6) + x1) << 8) + e);
            short4v v10 = *(const short4v*)(xsrc + (((size_t)(y1 << 6) + x0) << 8) + e);
            short4v v11 = *(const short4v*)(xsrc + (((size_t)(y1 << 6) + x1) << 8) + e);
            short4v pk;
#pragma unroll
            for (int jj = 0; jj < 4; ++jj) {
                float v = w00 * s2f(v00[jj]) + w01 * s2f(v01[jj])
                        + w10 * s2f(v10[jj]) + w11 * s2f(v11[jj]);
                pk[jj] = f2s(v);
            }
            *(short4v*)&xupS[(l << 8)
                    + ((((e >> 3) ^ (l & 7)) << 3) | (e & 4))] = pk;
        }
    }
    __syncthreads();

    // --- phase 2: comp MFMA; M = 64 tile-linear px mapped to 10x10 rows ---
    const int r0 = (((     n) >> 3) + 1) * 10 + (n & 7) + 1;
    const int r1 = (((16 + n) >> 3) + 1) * 10 + (n & 7) + 1;
    const int r2 = (((32 + n) >> 3) + 1) * 10 + (n & 7) + 1;
    const int r3 = (((48 + n) >> 3) + 1) * 10 + (n & 7) + 1;
    f32x4 accA0 = {0.f,0.f,0.f,0.f}, accA1 = {0.f,0.f,0.f,0.f};
    f32x4 accB0 = {0.f,0.f,0.f,0.f}, accB1 = {0.f,0.f,0.f,0.f};
#pragma unroll
    for (int kc = 0; kc < 8; ++kc) {
        int sp = (kc << 2) + quad;
        short8 a0 = *(const short8*)&xupS[(r0 << 8) + ((sp ^ (r0 & 7)) << 3)];
        short8 a1 = *(const short8*)&xupS[(r1 << 8) + ((sp ^ (r1 & 7)) << 3)];
        short8 a2 = *(const short8*)&xupS[(r2 << 8) + ((sp ^ (r2 & 7)) << 3)];
        short8 a3 = *(const short8*)&xupS[(r3 << 8) + ((sp ^ (r3 & 7)) << 3)];
        accA0 = __builtin_amdgcn_mfma_f32_16x16x32_bf16(a0, bfrag[kc], accA0, 0, 0, 0);
        accA1 = __builtin_amdgcn_mfma_f32_16x16x32_bf16(a1, bfrag[kc], accA1, 0, 0, 0);
        accB0 = __builtin_amdgcn_mfma_f32_16x16x32_bf16(a2, bfrag[kc], accB0, 0, 0, 0);
        accB1 = __builtin_amdgcn_mfma_f32_16x16x32_bf16(a3, bfrag[kc], accB1, 0, 0, 0);
    }
#pragma unroll
    for (int r = 0; r < 4; ++r) {
        smc[     quad * 4 + r][ocb + n] = accA0[r] + bias;
        smc[16 + quad * 4 + r][ocb + n] = accA1[r] + bias;
        smc[32 + quad * 4 + r][ocb + n] = accB0[r] + bias;
        smc[48 + quad * 4 + r][ocb + n] = accB1[r] + bias;
    }
    __syncthreads();

    // --- phase 3: kern softmax (wave 0, -> LDS) / toff (waves 1..3) ---
    const int px = threadIdx.x & 63;    // tile-linear
    const int q = threadIdx.x >> 6;
    if (q == 0) {
        float a[9];
#pragma unroll
        for (int k = 0; k < 9; ++k) a[k] = fb[k];
        for (int c = 0; c < 64; ++c) {
            float v = smc[px][c];
            const float4* wr = reinterpret_cast<const float4*>(&fwS[c * 12]);
            float4 w0 = wr[0], w1 = wr[1];
            float w8 = fwS[c * 12 + 8];
            a[0] += v * w0.x; a[1] += v * w0.y; a[2] += v * w0.z; a[3] += v * w0.w;
            a[4] += v * w1.x; a[5] += v * w1.y; a[6] += v * w1.z; a[7] += v * w1.w;
            a[8] += v * w8;
        }
        float mx = a[0];
#pragma unroll
        for (int k = 1; k < 9; ++k) mx = fmaxf(mx, a[k]);
        float s = 0.f;
#pragma unroll
        for (int k = 0; k < 9; ++k) { a[k] = expf(a[k] - mx); s += a[k]; }
        float inv = 1.f / s;
#pragma unroll
        for (int k = 0; k < 9; ++k) kernS[px][k] = f2s(a[k] * inv);
    } else {
        const int oc0 = (q == 3) ? 6 : (q - 1) * 3;
        const int noc = (q == 3) ? 2 : 3;
        float o[3], aa[3];
        for (int i = 0; i < noc; ++i) { o[i] = tb[oc0 + i]; aa[i] = tab[oc0 + i]; }
        for (int c = 0; c < 64; ++c) {
            float v = smc[px][c];
            const float* wr = &swS[c << 4];
#pragma unroll 3
            for (int i = 0; i < noc; ++i) {
                o[i]  += v * wr[2 * (oc0 + i)];
                aa[i] += v * wr[2 * (oc0 + i) + 1];
            }
        }
        int hw = ((ty * 8 + (px >> 3)) << 7) + tx * 8 + (px & 7);
        for (int i = 0; i < noc; ++i)
            toff[((size_t)((b << 3) + oc0 + i) << 14) + hw] =
                o[i] * (1.f / (1.f + expf(-aa[i])));
    }
    __syncthreads();

    // --- phase 4: 3x3 dynamic filter from LDS -> xfilt ---
    {
        const int chunk = threadIdx.x & 31;       // 8-channel chunk
        const int pxg = threadIdx.x >> 5;         // 0..7
#pragma unroll
        for (int it = 0; it < 8; ++it) {
            int p = (pxg << 3) + it;              // tile-linear px
            int ly = p >> 3, lx = p & 7;
            int gh = ty * 8 + ly, gw = tx * 8 + lx;
            float wk[9];
            short8 k8 = *(const short8*)&kernS[p][0];
#pragma unroll
            for (int k = 0; k < 8; ++k) wk[k] = s2f(k8[k]);
            wk[8] = s2f(kernS[p][8]);
            float ymask[3] = { gh > 0 ? 1.f : 0.f, 1.f, gh < 127 ? 1.f : 0.f };
            float xmask[3] = { gw > 0 ? 1.f : 0.f, 1.f, gw < 127 ? 1.f : 0.f };
            float sum[8];
#pragma unroll
            for (int jj = 0; jj < 8; ++jj) sum[jj] = 0.f;
#pragma unroll
            for (int dy = 0; dy < 3; ++dy) {
#pragma unroll
                for (int dx = 0; dx < 3; ++dx) {
                    float wgt = wk[dy * 3 + dx] * ymask[dy] * xmask[dx];
                    int r = (ly + dy) * 10 + lx + dx;
                    short8 v = *(const short8*)&xupS[(r << 8)
                                + (((chunk ^ (r & 7))) << 3)];
#pragma unroll
                    for (int jj = 0; jj < 8; ++jj) sum[jj] += wgt * s2f(v[jj]);
                }
            }
            short8 pk;
#pragma unroll
            for (int jj = 0; jj < 8; ++jj) pk[jj] = f2s(sum[jj]);
            int hw = (gh << 7) + gw;
            *(short8*)((short*)xfilt + ((size_t)((b << 14) + hw) << 8)
                       + chunk * 8) = pk;
        }
    }
}

// ---------------------------------------------------------------------------
// K6: trim_op -> out (b,256,16384) fp32
// ---------------------------------------------------------------------------
__global__ __launch_bounds__(256) void k6_trim(const bf16* __restrict__ xfilt,
        const float* __restrict__ toff, float* __restrict__ out)
{
    __shared__ float sm[32][260];
    int b = blockIdx.x >> 9;
    int hw0 = (blockIdx.x & 511) << 5;
    int wave = threadIdx.x >> 6, lane = threadIdx.x & 63;
    int e = lane * 4;
    int g = lane >> 4;
    const short* xb = (const short*)xfilt + ((size_t)(b * HWD) << 8);
    const float* tfx = toff + ((size_t)(b * 8 + 2 * g)     << 14);
    const float* tfy = toff + ((size_t)(b * 8 + 2 * g + 1) << 14);

    for (int i = 0; i < 8; ++i) {
        int pp = wave * 8 + i;
        int hw = hw0 + pp;
        int h = hw >> 7, w = hw & 127;
        float ox = tfx[hw], oy = tfy[hw];
        float ix = fminf(fmaxf(w + ox, 0.f), 127.f);
        float iy = fminf(fmaxf(h + oy, 0.f), 127.f);
        float x0f = floorf(ix), y0f = floorf(iy);
        float fx = ix - x0f, fy = iy - y0f;
        int x0 = (int)x0f, y0 = (int)y0f;
        int x1 = min(x0 + 1, 127), y1 = min(y0 + 1, 127);
        float w00 = (1.f - fx) * (1.f - fy), w01 = fx * (1.f - fy);
        float w10 = (1.f - fx) * fy,        w11 = fx * fy;
        short4v v00 = *(const short4v*)(xb + (((size_t)(y0 << 7) + x0) << 8) + e);
        short4v v01 = *(const short4v*)(xb + (((size_t)(y0 << 7) + x1) << 8) + e);
        short4v v10 = *(const short4v*)(xb + (((size_t)(y1 << 7) + x0) << 8) + e);
        short4v v11 = *(const short4v*)(xb + (((size_t)(y1 << 7) + x1) << 8) + e);
#pragma unroll
        for (int j = 0; j < 4; ++j) {
            sm[pp][e + j] = w00 * s2f(v00[j]) + w01 * s2f(v01[j])
                          + w10 * s2f(v10[j]) + w11 * s2f(v11[j]);
        }
    }
    __syncthreads();
    int lp = threadIdx.x & 31;
    int c0 = (threadIdx.x >> 5) << 5;
    float* ob = out + (((size_t)b << 8) << 14) + hw0 + lp;
#pragma unroll 8
    for (int k = 0; k < 32; ++k) {
        int c = c0 + k;
        ob[(size_t)c << 14] = sm[lp][c];
    }
}

extern "C" void kernel_launch(void* const* d_in, const int* in_sizes, int n_in,
                              void* d_out, int out_size, void* d_ws, size_t ws_size,
                              hipStream_t stream)
{
    const float* x       = (const float*)d_in[0];
    const float* w_off   = (const float*)d_in[1];
    const float* b_off   = (const float*)d_in[2];
    const float* w_ast   = (const float*)d_in[3];
    const float* b_ast   = (const float*)d_in[4];
    const float* comp_w  = (const float*)d_in[5];
    const float* comp_b  = (const float*)d_in[6];
    const float* filt_w  = (const float*)d_in[7];
    const float* filt_b  = (const float*)d_in[8];
    const float* trim_w  = (const float*)d_in[9];
    const float* trim_b  = (const float*)d_in[10];
    const float* trim_aw = (const float*)d_in[11];
    const float* trim_ab = (const float*)d_in[12];
    float* out = (float*)d_out;

    char* ws = (char*)d_ws;
    float* offpm = (float*)(ws);                 // 2 MiB (b,4096,32)
    bf16*  xpm   = (bf16*) (ws + (2ull << 20));  // 8 MiB pixel-major (b,4096,256)
    bf16*  xfilt = (bf16*) (ws + (16ull << 20)); // 32 MiB pixel-major (b,hw,256)
    float* toff  = (float*)(ws + (48ull << 20)); // 2 MiB (b,8,16384)

    hipLaunchKernelGGL(k01_xpose_off, dim3(256),  dim3(512), 0, stream,
                       x, w_off, b_off, w_ast, b_ast, xpm, offpm);
    hipLaunchKernelGGL(k234_defsample_comp_filter, dim3(1024), dim3(256), 0, stream,
                       xpm, offpm, comp_w, comp_b, filt_w, filt_b,
                       trim_w, trim_b, trim_aw, trim_ab, xfilt, toff);
    hipLaunchKernelGGL(k6_trim,     dim3(2048),  dim3(256), 0, stream,
                       xfilt, toff, out);
}

// Round 3
// 170.393 us; speedup vs baseline: 1.0395x; 1.0395x over previous
//
#include <hip/hip_runtime.h>
#include <hip/hip_bf16.h>
#include <string.h>

typedef __hip_bfloat16 bf16;
typedef __attribute__((ext_vector_type(8))) short short8;
typedef __attribute__((ext_vector_type(4))) short short4v;
typedef __attribute__((ext_vector_type(4))) float f32x4;

__device__ __forceinline__ float s2f(short s) {
    return __uint_as_float(((unsigned)(unsigned short)s) << 16);
}
__device__ __forceinline__ short f2s(float v) {
    bf16 t = __float2bfloat16(v); short s; __builtin_memcpy(&s, &t, 2); return s;
}

#define HWD 16384    // 128*128

// ---------------------------------------------------------------------------
// K01: transpose x (b,256,4096) fp32 -> xpm (b,4096,256) bf16 via swizzled
// LDS tile, then MFMA the off/ast GEMM straight from LDS.
// grid 256 = 4 b * 64 tiles(64 px); 512 threads (8 waves: 2 m-halves x 4 N).
// ---------------------------------------------------------------------------
__global__ __launch_bounds__(512) void k01_xpose_off(const float* __restrict__ x,
        const float* __restrict__ w_off, const float* __restrict__ b_off,
        const float* __restrict__ w_ast, const float* __restrict__ b_ast,
        bf16* __restrict__ xpm, float* __restrict__ offpm)
{
    __shared__ __align__(16) short tileS[64 * 256];   // 32 KB, swizzled
    const int b = blockIdx.x >> 6;
    const int p0 = (blockIdx.x & 63) << 6;
    const int lane = threadIdx.x & 63;
    const int wave = threadIdx.x >> 6;      // 0..7
    const int n = lane & 15, quad = lane >> 4;
    const int wq = wave & 3;                // N-group
    const int mh = wave >> 2;               // m-half

    const int j = (wq << 4) + n, oc = j >> 1, kind = j & 1;
    short8 bfrag[8];
    const float* wrow = (kind ? w_ast : w_off) + oc * 256 + quad * 8;
#pragma unroll
    for (int kc = 0; kc < 8; ++kc) {
        float4 lo = *(const float4*)(wrow + kc * 32);
        float4 hi = *(const float4*)(wrow + kc * 32 + 4);
        short8 f;
        f[0] = f2s(lo.x); f[1] = f2s(lo.y); f[2] = f2s(lo.z); f[3] = f2s(lo.w);
        f[4] = f2s(hi.x); f[5] = f2s(hi.y); f[6] = f2s(hi.z); f[7] = f2s(hi.w);
        bfrag[kc] = f;
    }
    float bias = kind ? b_ast[oc] : b_off[oc];

    // --- phase 1: fill swizzled LDS tile ---
    {
        const float* xb = x + ((size_t)b << 20);
        const int lp = lane;
#pragma unroll
        for (int gg = 0; gg < 4; ++gg) {
            int cbase = (wave << 5) + (gg << 3);
            short8 pk;
#pragma unroll
            for (int jj = 0; jj < 8; ++jj)
                pk[jj] = f2s(xb[((size_t)(cbase + jj) << 12) + p0 + lp]);
            int slot = (cbase >> 3) ^ (lp & 7);
            *(short8*)&tileS[(lp << 8) + (slot << 3)] = pk;
        }
    }
    __syncthreads();

    // --- phase 2: coalesced xpm store from LDS ---
    {
        short* ob = (short*)xpm + ((size_t)((b << 12) + p0) << 8);
#pragma unroll
        for (int rr = 0; rr < 8; ++rr) {
            int r = (wave << 3) + rr;
            short4v v = *(const short4v*)&tileS[(r << 8)
                        + ((((lane >> 1) ^ (r & 7)) << 3) | ((lane & 1) << 2))];
            *(short4v*)(ob + ((size_t)r << 8) + (lane << 2)) = v;
        }
    }

    // --- phase 3: MFMA GEMM from LDS, gated epilogue -> offpm ---
    float* obase = offpm + ((size_t)(b << 12) << 5);
    f32x4 acc0 = {0.f, 0.f, 0.f, 0.f};
    f32x4 acc1 = {0.f, 0.f, 0.f, 0.f};
#pragma unroll
    for (int kc = 0; kc < 8; ++kc) {
        int slot = (((kc << 2) + quad) ^ (n & 7)) << 3;
        short8 a0 = *(const short8*)&tileS[((mh * 32 + n) << 8) + slot];
        short8 a1 = *(const short8*)&tileS[((mh * 32 + 16 + n) << 8) + slot];
        acc0 = __builtin_amdgcn_mfma_f32_16x16x32_bf16(a0, bfrag[kc], acc0, 0, 0, 0);
        acc1 = __builtin_amdgcn_mfma_f32_16x16x32_bf16(a1, bfrag[kc], acc1, 0, 0, 0);
    }
#pragma unroll
    for (int r = 0; r < 4; ++r) {
        float v0 = acc0[r] + bias;
        float v1 = acc1[r] + bias;
        float p0v = __shfl_xor(v0, 1, 64);
        float p1v = __shfl_xor(v1, 1, 64);
        if (!(n & 1)) {
            int px = p0 + mh * 32 + quad * 4 + r;
            obase[((size_t)px << 5) + oc] = v0 * (1.f / (1.f + expf(-p0v)));
            obase[((size_t)(px + 16) << 5) + oc] = v1 * (1.f / (1.f + expf(-p1v)));
        }
    }
}

// ---------------------------------------------------------------------------
// K234: def_sample(10x10 halo) + comp MFMA + kern/toff epilogue + 3x3 filter.
// grid 1024 = 4 b * 256 tiles(8x8 px); 512 threads (8 waves) for latency
// hiding: LDS 78KB -> 2 blocks/CU -> 16 waves/CU (~50% occ) vs 20% before.
// Gather: 16B loads, 32 lanes x 2 px per wave-iteration.
// ---------------------------------------------------------------------------
__global__ __launch_bounds__(512, 4) void k234_defsample_comp_filter(
        const bf16* __restrict__ xpm, const float* __restrict__ offpm,
        const float* __restrict__ cw, const float* __restrict__ cb,
        const float* __restrict__ fw_g, const float* __restrict__ fb,
        const float* __restrict__ tw, const float* __restrict__ tb,
        const float* __restrict__ taw, const float* __restrict__ tab,
        bf16* __restrict__ xfilt, float* __restrict__ toff)
{
    __shared__ __align__(16) short xupS[100 * 256];   // 50 KB, swizzled rows
    __shared__ __align__(16) float smc[64][65];       // comp redistribution
    __shared__ __align__(16) float fwS[64 * 12];
    __shared__ __align__(16) float swS[64 * 16];
    __shared__ __align__(16) short kernS[64][24];     // 16B-aligned rows

    for (int i = threadIdx.x; i < 64 * 12; i += 512) {
        int c = i / 12, k = i % 12;
        fwS[i] = (k < 9) ? fw_g[k * 64 + c] : 0.f;
    }
    for (int i = threadIdx.x; i < 64 * 16; i += 512) {
        int c = i >> 4, jj = i & 15;
        int oc = jj >> 1, kind = jj & 1;
        swS[i] = kind ? taw[oc * 64 + c] : tw[oc * 64 + c];
    }

    const int b = blockIdx.x >> 8;
    const int tile = blockIdx.x & 255;
    const int ty = tile >> 4, tx = tile & 15;
    const int lane = threadIdx.x & 63;
    const int wave = threadIdx.x >> 6;       // 0..7
    const int n = lane & 15, quad = lane >> 4;
    const int wq = wave & 3, mh = wave >> 2;
    const int ocb = wq << 4;

    // --- B fragments for comp GEMM (dup across mh) ---
    short8 bfrag[8];
    const float* wrow = cw + (ocb + n) * 256 + quad * 8;
#pragma unroll
    for (int kc = 0; kc < 8; ++kc) {
        float4 lo = *(const float4*)(wrow + kc * 32);
        float4 hi = *(const float4*)(wrow + kc * 32 + 4);
        short8 f;
        f[0] = f2s(lo.x); f[1] = f2s(lo.y); f[2] = f2s(lo.z); f[3] = f2s(lo.w);
        f[4] = f2s(hi.x); f[5] = f2s(hi.y); f[6] = f2s(hi.z); f[7] = f2s(hi.w);
        bfrag[kc] = f;
    }
    float bias = cb[ocb + n];

    // --- phase 1: gather halo pixels; 2 px per wave-iter, 16B loads ---
    {
        const short* xsrc = (const short*)xpm + ((size_t)b << 20);
        const int ph = lane >> 5;             // px half
        const int cl = lane & 31;             // 8-ch chunk
        const int e = cl << 3;                // shorts
        const int g = cl >> 3;                // offset group
        for (int l = (wave << 1) + ph; l < 100; l += 16) {
            int lhy = (l * 205) >> 11;        // l / 10
            int lwx = l - lhy * 10;
            int hy = ty * 8 - 1 + lhy;  hy = min(max(hy, 0), 127);
            int wx = tx * 8 - 1 + lwx;  wx = min(max(wx, 0), 127);
            int h = hy >> 1, w = wx >> 1;
            int och = (g << 3) + ((hy & 1) << 2) + ((wx & 1) << 1);
            const float* orow = offpm + ((size_t)((b << 12) + (h << 6) + w) << 5);
            float ox = orow[och], oy = orow[och + 1];
            float ix = (wx + 0.5f + ox) * 0.5f - 0.5f;
            float iy = (hy + 0.5f + oy) * 0.5f - 0.5f;
            ix = fminf(fmaxf(ix, 0.f), 63.f);
            iy = fminf(fmaxf(iy, 0.f), 63.f);
            float x0f = floorf(ix), y0f = floorf(iy);
            float fx = ix - x0f, fy = iy - y0f;
            int x0 = (int)x0f, y0 = (int)y0f;
            int x1 = min(x0 + 1, 63), y1 = min(y0 + 1, 63);
            float w00 = (1.f - fx) * (1.f - fy), w01 = fx * (1.f - fy);
            float w10 = (1.f - fx) * fy,        w11 = fx * fy;
            short8 v00 = *(const short8*)(xsrc + (((size_t)(y0 << 6) + x0) << 8) + e);
            short8 v01 = *(const short8*)(xsrc + (((size_t)(y0 << 6) + x1) << 8) + e);
            short8 v10 = *(const short8*)(xsrc + (((size_t)(y1 << 6) + x0) << 8) + e);
            short8 v11 = *(const short8*)(xsrc + (((size_t)(y1 << 6) + x1) << 8) + e);
            short8 pk;
#pragma unroll
            for (int jj = 0; jj < 8; ++jj) {
                float v = w00 * s2f(v00[jj]) + w01 * s2f(v01[jj])
                        + w10 * s2f(v10[jj]) + w11 * s2f(v11[jj]);
                pk[jj] = f2s(v);
            }
            int slot = cl ^ (l & 7);
            *(short8*)&xupS[(l << 8) + (slot << 3)] = pk;
        }
    }
    __syncthreads();

    // --- phase 2: comp MFMA; wave (mh,wq) does m-half mh, cols wq*16 ---
    const int m0 = mh << 5;
    const int pA = m0 + n, pB = m0 + 16 + n;
    const int rA = ((pA >> 3) + 1) * 10 + (pA & 7) + 1;
    const int rB = ((pB >> 3) + 1) * 10 + (pB & 7) + 1;
    f32x4 acc0 = {0.f,0.f,0.f,0.f}, acc1 = {0.f,0.f,0.f,0.f};
#pragma unroll
    for (int kc = 0; kc < 8; ++kc) {
        int sp = (kc << 2) + quad;
        short8 a0 = *(const short8*)&xupS[(rA << 8) + ((sp ^ (rA & 7)) << 3)];
        short8 a1 = *(const short8*)&xupS[(rB << 8) + ((sp ^ (rB & 7)) << 3)];
        acc0 = __builtin_amdgcn_mfma_f32_16x16x32_bf16(a0, bfrag[kc], acc0, 0, 0, 0);
        acc1 = __builtin_amdgcn_mfma_f32_16x16x32_bf16(a1, bfrag[kc], acc1, 0, 0, 0);
    }
#pragma unroll
    for (int r = 0; r < 4; ++r) {
        smc[m0 +      quad * 4 + r][ocb + n] = acc0[r] + bias;
        smc[m0 + 16 + quad * 4 + r][ocb + n] = acc1[r] + bias;
    }
    __syncthreads();

    // --- phase 3: kern softmax (wave 0) / toff (waves 1..4) ---
    const int px = lane;
    const int q = wave;
    if (q == 0) {
        float a[9];
#pragma unroll
        for (int k = 0; k < 9; ++k) a[k] = fb[k];
        for (int c = 0; c < 64; ++c) {
            float v = smc[px][c];
            const float4* wr = reinterpret_cast<const float4*>(&fwS[c * 12]);
            float4 w0 = wr[0], w1 = wr[1];
            float w8 = fwS[c * 12 + 8];
            a[0] += v * w0.x; a[1] += v * w0.y; a[2] += v * w0.z; a[3] += v * w0.w;
            a[4] += v * w1.x; a[5] += v * w1.y; a[6] += v * w1.z; a[7] += v * w1.w;
            a[8] += v * w8;
        }
        float mx = a[0];
#pragma unroll
        for (int k = 1; k < 9; ++k) mx = fmaxf(mx, a[k]);
        float s = 0.f;
#pragma unroll
        for (int k = 0; k < 9; ++k) { a[k] = expf(a[k] - mx); s += a[k]; }
        float inv = 1.f / s;
#pragma unroll
        for (int k = 0; k < 9; ++k) kernS[px][k] = f2s(a[k] * inv);
    } else if (q <= 4) {
        const int oc0 = (q - 1) << 1;
        float o[2], aa[2];
#pragma unroll
        for (int i = 0; i < 2; ++i) { o[i] = tb[oc0 + i]; aa[i] = tab[oc0 + i]; }
        for (int c = 0; c < 64; ++c) {
            float v = smc[px][c];
            const float* wr = &swS[c << 4];
#pragma unroll
            for (int i = 0; i < 2; ++i) {
                o[i]  += v * wr[2 * (oc0 + i)];
                aa[i] += v * wr[2 * (oc0 + i) + 1];
            }
        }
        int hw = ((ty * 8 + (px >> 3)) << 7) + tx * 8 + (px & 7);
#pragma unroll
        for (int i = 0; i < 2; ++i)
            toff[((size_t)((b << 3) + oc0 + i) << 14) + hw] =
                o[i] * (1.f / (1.f + expf(-aa[i])));
    }
    __syncthreads();

    // --- phase 4: 3x3 dynamic filter from LDS -> xfilt ---
    {
        const int chunk = threadIdx.x & 31;       // 8-channel chunk
        const int pxg = threadIdx.x >> 5;         // 0..15
#pragma unroll
        for (int it = 0; it < 4; ++it) {
            int p = (pxg << 2) + it;              // tile-linear px
            int ly = p >> 3, lx = p & 7;
            int gh = ty * 8 + ly, gw = tx * 8 + lx;
            float wk[9];
            short8 k8 = *(const short8*)&kernS[p][0];
#pragma unroll
            for (int k = 0; k < 8; ++k) wk[k] = s2f(k8[k]);
            wk[8] = s2f(kernS[p][8]);
            float ymask[3] = { gh > 0 ? 1.f : 0.f, 1.f, gh < 127 ? 1.f : 0.f };
            float xmask[3] = { gw > 0 ? 1.f : 0.f, 1.f, gw < 127 ? 1.f : 0.f };
            float sum[8];
#pragma unroll
            for (int jj = 0; jj < 8; ++jj) sum[jj] = 0.f;
#pragma unroll
            for (int dy = 0; dy < 3; ++dy) {
#pragma unroll
                for (int dx = 0; dx < 3; ++dx) {
                    float wgt = wk[dy * 3 + dx] * ymask[dy] * xmask[dx];
                    int r = (ly + dy) * 10 + lx + dx;
                    short8 v = *(const short8*)&xupS[(r << 8)
                                + (((chunk ^ (r & 7))) << 3)];
#pragma unroll
                    for (int jj = 0; jj < 8; ++jj) sum[jj] += wgt * s2f(v[jj]);
                }
            }
            short8 pk;
#pragma unroll
            for (int jj = 0; jj < 8; ++jj) pk[jj] = f2s(sum[jj]);
            int hw = (gh << 7) + gw;
            *(short8*)((short*)xfilt + ((size_t)((b << 14) + hw) << 8)
                       + chunk * 8) = pk;
        }
    }
}

// ---------------------------------------------------------------------------
// K6: trim_op -> out (b,256,16384) fp32. 512 threads: 2 px per wave-iter,
// 16B tap loads, 2 gather iterations per lane.
// ---------------------------------------------------------------------------
__global__ __launch_bounds__(512, 4) void k6_trim(const bf16* __restrict__ xfilt,
        const float* __restrict__ toff, float* __restrict__ out)
{
    __shared__ __align__(16) float sm[32][260];
    int b = blockIdx.x >> 9;
    int hw0 = (blockIdx.x & 511) << 5;
    int wave = threadIdx.x >> 6, lane = threadIdx.x & 63;
    int ph = lane >> 5;             // px half
    int cl = lane & 31;             // 8-ch chunk
    int e = cl << 3;                // shorts
    int g = cl >> 3;                // trim group (64 ch each)
    const short* xb = (const short*)xfilt + ((size_t)(b * HWD) << 8);
    const float* tfx = toff + ((size_t)(b * 8 + 2 * g)     << 14);
    const float* tfy = toff + ((size_t)(b * 8 + 2 * g + 1) << 14);

#pragma unroll
    for (int i = 0; i < 2; ++i) {
        int pp = (wave << 2) + (i << 1) + ph;
        int hw = hw0 + pp;
        int h = hw >> 7, w = hw & 127;
        float ox = tfx[hw], oy = tfy[hw];
        float ix = fminf(fmaxf(w + ox, 0.f), 127.f);
        float iy = fminf(fmaxf(h + oy, 0.f), 127.f);
        float x0f = floorf(ix), y0f = floorf(iy);
        float fx = ix - x0f, fy = iy - y0f;
        int x0 = (int)x0f, y0 = (int)y0f;
        int x1 = min(x0 + 1, 127), y1 = min(y0 + 1, 127);
        float w00 = (1.f - fx) * (1.f - fy), w01 = fx * (1.f - fy);
        float w10 = (1.f - fx) * fy,        w11 = fx * fy;
        short8 v00 = *(const short8*)(xb + (((size_t)(y0 << 7) + x0) << 8) + e);
        short8 v01 = *(const short8*)(xb + (((size_t)(y0 << 7) + x1) << 8) + e);
        short8 v10 = *(const short8*)(xb + (((size_t)(y1 << 7) + x0) << 8) + e);
        short8 v11 = *(const short8*)(xb + (((size_t)(y1 << 7) + x1) << 8) + e);
        float4 lo, hi;
        lo.x = w00 * s2f(v00[0]) + w01 * s2f(v01[0]) + w10 * s2f(v10[0]) + w11 * s2f(v11[0]);
        lo.y = w00 * s2f(v00[1]) + w01 * s2f(v01[1]) + w10 * s2f(v10[1]) + w11 * s2f(v11[1]);
        lo.z = w00 * s2f(v00[2]) + w01 * s2f(v01[2]) + w10 * s2f(v10[2]) + w11 * s2f(v11[2]);
        lo.w = w00 * s2f(v00[3]) + w01 * s2f(v01[3]) + w10 * s2f(v10[3]) + w11 * s2f(v11[3]);
        hi.x = w00 * s2f(v00[4]) + w01 * s2f(v01[4]) + w10 * s2f(v10[4]) + w11 * s2f(v11[4]);
        hi.y = w00 * s2f(v00[5]) + w01 * s2f(v01[5]) + w10 * s2f(v10[5]) + w11 * s2f(v11[5]);
        hi.z = w00 * s2f(v00[6]) + w01 * s2f(v01[6]) + w10 * s2f(v10[6]) + w11 * s2f(v11[6]);
        hi.w = w00 * s2f(v00[7]) + w01 * s2f(v01[7]) + w10 * s2f(v10[7]) + w11 * s2f(v11[7]);
        *(float4*)&sm[pp][e]     = lo;
        *(float4*)&sm[pp][e + 4] = hi;
    }
    __syncthreads();
    int lp = threadIdx.x & 31;
    int cg = threadIdx.x >> 5;          // 0..15, 16 channels each
    float* ob = out + ((size_t)b << 22) + hw0 + lp;
#pragma unroll 8
    for (int k = 0; k < 16; ++k) {
        int c = (cg << 4) + k;
        ob[(size_t)c << 14] = sm[lp][c];
    }
}

extern "C" void kernel_launch(void* const* d_in, const int* in_sizes, int n_in,
                              void* d_out, int out_size, void* d_ws, size_t ws_size,
                              hipStream_t stream)
{
    const float* x       = (const float*)d_in[0];
    const float* w_off   = (const float*)d_in[1];
    const float* b_off   = (const float*)d_in[2];
    const float* w_ast   = (const float*)d_in[3];
    const float* b_ast   = (const float*)d_in[4];
    const float* comp_w  = (const float*)d_in[5];
    const float* comp_b  = (const float*)d_in[6];
    const float* filt_w  = (const float*)d_in[7];
    const float* filt_b  = (const float*)d_in[8];
    const float* trim_w  = (const float*)d_in[9];
    const float* trim_b  = (const float*)d_in[10];
    const float* trim_aw = (const float*)d_in[11];
    const float* trim_ab = (const float*)d_in[12];
    float* out = (float*)d_out;

    char* ws = (char*)d_ws;
    float* offpm = (float*)(ws);                 // 2 MiB (b,4096,32)
    bf16*  xpm   = (bf16*) (ws + (2ull << 20));  // 8 MiB pixel-major (b,4096,256)
    bf16*  xfilt = (bf16*) (ws + (16ull << 20)); // 32 MiB pixel-major (b,hw,256)
    float* toff  = (float*)(ws + (48ull << 20)); // 2 MiB (b,8,16384)

    hipLaunchKernelGGL(k01_xpose_off, dim3(256),  dim3(512), 0, stream,
                       x, w_off, b_off, w_ast, b_ast, xpm, offpm);
    hipLaunchKernelGGL(k234_defsample_comp_filter, dim3(1024), dim3(512), 0, stream,
                       xpm, offpm, comp_w, comp_b, filt_w, filt_b,
                       trim_w, trim_b, trim_aw, trim_ab, xfilt, toff);
    hipLaunchKernelGGL(k6_trim,     dim3(2048),  dim3(512), 0, stream,
                       xfilt, toff, out);
}